// Round 2
// 272.446 us; speedup vs baseline: 1.1293x; 1.1293x over previous
//
#include <hip/hip_runtime.h>

#define BB   128
#define DD   128
#define OUTN 100000
#define KP1  4097          // K+1
#define TEMP 0.07f

#define NSB   8320         // score blocks: 65 k-chunks * 128 b   (65*64 >= 4097)
#define N1F4  3200000      // OUTN*DD/4  (float4 elements in one memory)
#define NF4   6400000      // both memories
#define NSCALE_BLK 4097    // 4097*256 == 2*BB*KP1 exactly

// native vector type usable with __builtin_nontemporal_store
typedef float vfloat4 __attribute__((ext_vector_type(4)));

// ---------------------------------------------------------------------------
// Fused kernel: coalesced gather+dot+exp (8 lanes per (b,k) pair) PLUS the
// streaming memory->out copy, interleaved so the copy's streaming bandwidth
// fills the latency stalls of the random row gather.
//
// Layout: blockIdx.x = sb in [0, NSB). b = sb & 127, chunk = sb >> 7.
// Each block handles 64 consecutive k (2 iterations x 32 pairs); each pair
// is owned by an 8-lane group: lane g loads 64 contiguous bytes of the row,
// so a wave reads whole 512B rows coalesced. Dot completed via shfl tree.
// ---------------------------------------------------------------------------
__global__ __launch_bounds__(256) void fused_kernel(
    const float* __restrict__ z1,
    const float* __restrict__ mem2,
    const float* __restrict__ mem3,
    const int*   __restrict__ y,
    const int*   __restrict__ idx,
    float* __restrict__ out,     // s2 at [0, B*KP1), s3 at [B*KP1, 2*B*KP1)
    float* __restrict__ part)    // part[0..63]=sum2 buckets, part[64..127]=sum3
{
    const int sb    = blockIdx.x;
    const int b     = sb & (BB - 1);
    const int chunk = sb >> 7;              // 0..64
    const int tid   = threadIdx.x;
    const int g     = tid & 7;              // lane within 8-lane group
    const int grp   = tid >> 3;             // pair slot 0..31

    // z1 fragment for this lane: 16 consecutive floats at element g*16
    const float4* zz = (const float4*)(z1 + (size_t)b * DD + g * 16);
    const float4 z0 = zz[0], zv1 = zz[1], zv2 = zz[2], zv3 = zz[3];

    const int yb = y[b];

    float acc2 = 0.f, acc3 = 0.f;

    for (int it = 0; it < 2; ++it) {
        const int k = chunk * 64 + it * 32 + grp;
        const bool valid = (k < KP1);
        int j = 0;
        if (valid) j = (k == 0) ? yb : idx[b * KP1 + k];

        const float4* r2 = (const float4*)(mem2 + (size_t)j * DD + g * 16);
        const float4* r3 = (const float4*)(mem3 + (size_t)j * DD + g * 16);
        const float4 a0 = r2[0], a1 = r2[1], a2 = r2[2], a3 = r2[3];
        const float4 c0 = r3[0], c1 = r3[1], c2 = r3[2], c3 = r3[3];

        float d2 = a0.x*z0.x  + a0.y*z0.y  + a0.z*z0.z  + a0.w*z0.w
                 + a1.x*zv1.x + a1.y*zv1.y + a1.z*zv1.z + a1.w*zv1.w
                 + a2.x*zv2.x + a2.y*zv2.y + a2.z*zv2.z + a2.w*zv2.w
                 + a3.x*zv3.x + a3.y*zv3.y + a3.z*zv3.z + a3.w*zv3.w;
        float d3 = c0.x*z0.x  + c0.y*z0.y  + c0.z*z0.z  + c0.w*z0.w
                 + c1.x*zv1.x + c1.y*zv1.y + c1.z*zv1.z + c1.w*zv1.w
                 + c2.x*zv2.x + c2.y*zv2.y + c2.z*zv2.z + c2.w*zv2.w
                 + c3.x*zv3.x + c3.y*zv3.y + c3.z*zv3.z + c3.w*zv3.w;

        // reduce across the 8-lane group (xor masks < 8 stay in-group)
        d2 += __shfl_xor(d2, 1);  d3 += __shfl_xor(d3, 1);
        d2 += __shfl_xor(d2, 2);  d3 += __shfl_xor(d3, 2);
        d2 += __shfl_xor(d2, 4);  d3 += __shfl_xor(d3, 4);

        if (valid && g == 0) {
            const float s2 = expf(d2 * (1.0f / TEMP));
            const float s3 = expf(d3 * (1.0f / TEMP));
            out[b * KP1 + k]            = s2;   // 8 leaders/wave write 8
            out[BB * KP1 + b * KP1 + k] = s3;   // consecutive floats: coalesced
            acc2 += s2;
            acc3 += s3;
        }
    }

    // ---- streaming copy slice (fills BW while other waves stall on gathers)
    {
        const vfloat4* m2f = (const vfloat4*)mem2;
        const vfloat4* m3f = (const vfloat4*)mem3;
        vfloat4* dstf = (vfloat4*)(out + 2 * BB * KP1);
        for (int i = sb * 256 + tid; i < NF4; i += NSB * 256) {
            const vfloat4 v = (i < N1F4) ? m2f[i] : m3f[i - N1F4];
            __builtin_nontemporal_store(v, dstf + i);  // don't evict gather rows
        }
    }

    // ---- block partial sum of s for Z (leaders live at lanes 0,8,...,56)
    acc2 += __shfl_xor(acc2, 8);   acc3 += __shfl_xor(acc3, 8);
    acc2 += __shfl_xor(acc2, 16);  acc3 += __shfl_xor(acc3, 16);
    acc2 += __shfl_xor(acc2, 32);  acc3 += __shfl_xor(acc3, 32);

    __shared__ float w2s[4], w3s[4];
    const int wave = tid >> 6;
    const int lane = tid & 63;
    if (lane == 0) { w2s[wave] = acc2; w3s[wave] = acc3; }
    __syncthreads();
    if (tid == 0) {
        const float t2 = w2s[0] + w2s[1] + w2s[2] + w2s[3];
        const float t3 = w3s[0] + w3s[1] + w3s[2] + w3s[3];
        const int slot = sb & 63;
        atomicAdd(&part[slot],      t2);
        atomicAdd(&part[64 + slot], t3);
    }
}

// ---------------------------------------------------------------------------
// Kernel B: block zones. Blocks [0, 4097): I = s * (B*KP1)/(OUTN*sum).
// Blocks [4097, 4225): row update for b = blockIdx - 4097 (one wave).
// Disjoint output regions; runs after fused_kernel in-stream.
// ---------------------------------------------------------------------------
__global__ __launch_bounds__(256) void scale_update_kernel(
    const float* __restrict__ z2,
    const float* __restrict__ z3,
    const float* __restrict__ mem2,
    const float* __restrict__ mem3,
    const int*   __restrict__ y,
    float* __restrict__ out,
    const float* __restrict__ part)
{
    if (blockIdx.x < NSCALE_BLK) {
        __shared__ float sc[2];
        if (threadIdx.x == 0) {
            float t2 = 0.f, t3 = 0.f;
            for (int i = 0; i < 64; ++i) { t2 += part[i]; t3 += part[64 + i]; }
            sc[0] = (float)((double)(BB * KP1) / ((double)OUTN * (double)t2));
            sc[1] = (float)((double)(BB * KP1) / ((double)OUTN * (double)t3));
        }
        __syncthreads();
        const int i = blockIdx.x * 256 + threadIdx.x;   // always < 2*BB*KP1
        out[i] *= sc[(i < BB * KP1) ? 0 : 1];
        return;
    }

    // ---- update path: pos = 2*z - mem[y]  (momentum = -1), L2-normalize
    const int b    = blockIdx.x - NSCALE_BLK;
    const int lane = threadIdx.x;
    if (lane >= 64) return;
    const int yb = y[b];

    for (int bp = b + 1; bp < BB; ++bp)
        if (y[bp] == yb) return;    // last-write-wins on duplicate y

    float* out2 = out + 2 * BB * KP1;
    float* out3 = out2 + OUTN * DD;

    const float2 m2 = *(const float2*)(mem2 + (size_t)yb * DD + 2 * lane);
    const float2 m3 = *(const float2*)(mem3 + (size_t)yb * DD + 2 * lane);
    const float2 a2 = *(const float2*)(z2 + b * DD + 2 * lane);
    const float2 a3 = *(const float2*)(z3 + b * DD + 2 * lane);

    float2 p2, p3;
    p2.x = 2.f * a2.x - m2.x;  p2.y = 2.f * a2.y - m2.y;
    p3.x = 2.f * a3.x - m3.x;  p3.y = 2.f * a3.y - m3.y;

    float ss2 = p2.x * p2.x + p2.y * p2.y;
    float ss3 = p3.x * p3.x + p3.y * p3.y;
    #pragma unroll
    for (int off = 32; off > 0; off >>= 1) {
        ss2 += __shfl_xor(ss2, off);
        ss3 += __shfl_xor(ss3, off);
    }
    const float inv2 = 1.f / sqrtf(ss2);
    const float inv3 = 1.f / sqrtf(ss3);

    float2 w2, w3;
    w2.x = p2.x * inv2;  w2.y = p2.y * inv2;
    w3.x = p3.x * inv3;  w3.y = p3.y * inv3;
    *(float2*)(out2 + (size_t)yb * DD + 2 * lane) = w2;
    *(float2*)(out3 + (size_t)yb * DD + 2 * lane) = w3;
}

// ---------------------------------------------------------------------------
extern "C" void kernel_launch(void* const* d_in, const int* in_sizes, int n_in,
                              void* d_out, int out_size, void* d_ws, size_t ws_size,
                              hipStream_t stream)
{
    const float* z1   = (const float*)d_in[0];
    const float* z2   = (const float*)d_in[1];
    const float* z3   = (const float*)d_in[2];
    const float* mem2 = (const float*)d_in[3];
    const float* mem3 = (const float*)d_in[4];
    const int*   y    = (const int*)d_in[5];
    const int*   idx  = (const int*)d_in[6];
    float*       out  = (float*)d_out;
    float*       part = (float*)d_ws;

    hipMemsetAsync(d_ws, 0, 128 * sizeof(float), stream);

    // A: coalesced gather scores + streaming copy, fused
    fused_kernel<<<NSB, 256, 0, stream>>>(z1, mem2, mem3, y, idx, out, part);

    // B: scale scores by Z + scatter updated rows (block zones)
    scale_update_kernel<<<NSCALE_BLK + BB, 256, 0, stream>>>(
        z2, z3, mem2, mem3, y, out, part);
}